// Round 5
// baseline (176.669 us; speedup 1.0000x reference)
//
#include <hip/hip_runtime.h>
#include <hip/hip_bf16.h>

// CapsuleLayer on MI355X — barrier-free MFMA implicit-GEMM, v2.
// b stays 0 (faithful torch bug) => one dense conv 64ci -> 128co, 5x5, pad 2,
// then v = squash_z1(p/(8*cnt)) and transpose to [N, t1, z1, H, W].
// 16x16 pixel tile/block, 1024 thr = 16 waves (8M x 2N). A staged once in LDS
// (stride 72 ushorts = 144 B: 16B-aligned b128, uniform banks, scalar offsets).
// B register-prefetched from L1/L2-hot Wr2. One barrier total.

#define CO 128

typedef __attribute__((ext_vector_type(8))) short bf16x8;
typedef __attribute__((ext_vector_type(4))) float f32x4;

// ---- W fp32 [t0][co][z0][5][5] -> Wr2 bf16 [kk][co][ci]
__global__ __launch_bounds__(256) void k_reorder(const float* __restrict__ Wsrc,
                                                 ushort* __restrict__ Wr2) {
    int idx = blockIdx.x * 256 + threadIdx.x;   // (kk*128+co)*64+ci
    if (idx >= 25 * 128 * 64) return;
    int ci = idx & 63;
    int r  = idx >> 6;
    int co = r & 127;
    int kk = r >> 7;
    int t0 = ci >> 4, z0 = ci & 15;
    __hip_bfloat16 b = __float2bfloat16(Wsrc[((t0 * CO + co) * 16 + z0) * 25 + kk]);
    Wr2[idx] = *(ushort*)&b;
}

// ---- main: grid 256 = 4(n) x 8(by) x 8(bx), 1024 thr = 16 waves (8M x 2N)
// wave: wm = wid>>1 -> image rows [h0+wm*2, +2); wn = wid&1 -> co [wn*64, +64)
__global__ __launch_bounds__(1024) void k_caps(const float* __restrict__ u,
                                               const ushort* __restrict__ Wr2,
                                               float* __restrict__ out) {
    // [p = rr*20+cc][ci] , row stride 72 ushorts (144 B = 9x16 B: b128-aligned,
    // frag-read start banks 4*(m16+q)%32 -> uniform 8 dwords/bank). 57.6 KB.
    __shared__ alignas(16) ushort As[400 * 72];

    int tid = threadIdx.x;
    int bid = blockIdx.x;
    int bx = bid & 7, by = (bid >> 3) & 7, n = bid >> 6;
    int h0 = by * 16, w0 = bx * 16;

    const float* ub = u + (size_t)n * (64 * 128 * 128);

    // ---- stage A: 20x20 pixels (halo 2, zero OOB) x 64 ci, fp32 -> bf16.
    // e = (rr*64 + ci)*20 + cc: lanes sweep cc (20 contiguous floats per row)
    // -> ~4 memory transactions per wave instruction.
    for (int e = tid; e < 25600; e += 1024) {
        int cc = e % 20;
        int t  = e / 20;
        int ci = t & 63;
        int rr = t >> 6;
        int hh = h0 + rr - 2, ww = w0 + cc - 2;
        float v = 0.f;
        if ((unsigned)hh < 128u && (unsigned)ww < 128u)
            v = ub[((ci << 7) + hh) * 128 + ww];
        __hip_bfloat16 bv = __float2bfloat16(v);
        As[(rr * 20 + cc) * 72 + ci] = *(ushort*)&bv;
    }
    __syncthreads();   // the ONLY barrier

    int lane = tid & 63, wid = tid >> 6;
    int wm = wid >> 1;           // 0..7
    int wn = wid & 1;            // 0..1
    int q = lane >> 4, m16 = lane & 15;

    f32x4 acc[2][4] = {};

    // A frag (mi,kh,kw,ks): As[ aB(mi) + (kh*20+kw)*72 + ks*32 ]
    int aB0 = ((wm * 2) * 20 + m16) * 72 + q * 8;
    int aB1 = aB0 + 20 * 72;

    // B frag: Wr2[kk][co = wn*64 + ni*16 + m16][ci = ks*32 + q*8 ..+8]
    const ushort* bp = Wr2 + (wn * 64 + m16) * 64 + q * 8;
    bf16x8 bn[4];
#pragma unroll
    for (int ni = 0; ni < 4; ++ni) bn[ni] = *(const bf16x8*)(bp + ni * 1024);

    int soff = 0, kw = 0;
    for (int kk = 0; kk < 25; ++kk) {
        bf16x8 bc[4], a0, a1;
        // ---- ks = 0
#pragma unroll
        for (int ni = 0; ni < 4; ++ni) bc[ni] = bn[ni];
#pragma unroll
        for (int ni = 0; ni < 4; ++ni)
            bn[ni] = *(const bf16x8*)(bp + 32 + ni * 1024);
        a0 = *(const bf16x8*)(As + aB0 + soff);
        a1 = *(const bf16x8*)(As + aB1 + soff);
#pragma unroll
        for (int ni = 0; ni < 4; ++ni) {
            acc[0][ni] = __builtin_amdgcn_mfma_f32_16x16x32_bf16(a0, bc[ni], acc[0][ni], 0, 0, 0);
            acc[1][ni] = __builtin_amdgcn_mfma_f32_16x16x32_bf16(a1, bc[ni], acc[1][ni], 0, 0, 0);
        }
        // ---- ks = 1
#pragma unroll
        for (int ni = 0; ni < 4; ++ni) bc[ni] = bn[ni];
        if (kk < 24) {
#pragma unroll
            for (int ni = 0; ni < 4; ++ni)
                bn[ni] = *(const bf16x8*)(bp + 8192 + ni * 1024);
        }
        a0 = *(const bf16x8*)(As + aB0 + soff + 32);
        a1 = *(const bf16x8*)(As + aB1 + soff + 32);
#pragma unroll
        for (int ni = 0; ni < 4; ++ni) {
            acc[0][ni] = __builtin_amdgcn_mfma_f32_16x16x32_bf16(a0, bc[ni], acc[0][ni], 0, 0, 0);
            acc[1][ni] = __builtin_amdgcn_mfma_f32_16x16x32_bf16(a1, bc[ni], acc[1][ni], 0, 0, 0);
        }
        bp += 8192;
        bool roll = (kw == 4);
        soff += roll ? 1152 : 72;   // next kw, or next kh (20-4 rows * 72)
        kw = roll ? 0 : kw + 1;
    }

    // ---- epilogue: scale 1/(8*cnt), squash over z1 (= m16 lanes), store
    // D layout: row(m = image col) = q*4+reg, col(n = co) = m16
#pragma unroll
    for (int mi = 0; mi < 2; ++mi) {
        int h = h0 + wm * 2 + mi;
        int hlo = h - 2; if (hlo < 0) hlo = 0;
        int hhi = h + 2; if (hhi > 127) hhi = 127;
        float cnth = (float)(hhi - hlo + 1);
#pragma unroll
        for (int ni = 0; ni < 4; ++ni) {
            f32x4 cv = acc[mi][ni];
            float ov[4];
#pragma unroll
            for (int reg = 0; reg < 4; ++reg) {
                int w = w0 + q * 4 + reg;
                int wlo = w - 2; if (wlo < 0) wlo = 0;
                int whi = w + 2; if (whi > 127) whi = 127;
                float s = 1.f / (8.f * cnth * (float)(whi - wlo + 1));
                float pv = cv[reg] * s;
                float n2 = pv * pv;
                n2 += __shfl_xor(n2, 1);
                n2 += __shfl_xor(n2, 2);
                n2 += __shfl_xor(n2, 4);
                n2 += __shfl_xor(n2, 8);
                float fac = n2 / ((1.f + n2) * sqrtf(n2 + 1e-9f));
                ov[reg] = pv * fac;
            }
            int co = wn * 64 + ni * 16 + m16;
            *(float4*)(out + (((size_t)(n * CO + co)) << 14) + h * 128 + w0 + q * 4) =
                make_float4(ov[0], ov[1], ov[2], ov[3]);
        }
    }
}

extern "C" void kernel_launch(void* const* d_in, const int* in_sizes, int n_in,
                              void* d_out, int out_size, void* d_ws, size_t ws_size,
                              hipStream_t stream) {
    const float* u    = (const float*)d_in[0];
    const float* Wsrc = (const float*)d_in[1];
    float* out = (float*)d_out;
    ushort* Wr2 = (ushort*)d_ws;   // 409600 B

    k_reorder<<<800, 256, 0, stream>>>(Wsrc, Wr2);
    k_caps<<<256, 1024, 0, stream>>>(u, Wr2, out);
}

// Round 6
// 109.097 us; speedup vs baseline: 1.6194x; 1.6194x over previous
//
#include <hip/hip_runtime.h>
#include <hip/hip_bf16.h>

// CapsuleLayer on MI355X — MFMA implicit-GEMM, R3 skeleton + padded-80 LDS
// (HW-verified conflict-free frag pattern) + fully-unrolled kk loop (all LDS
// offsets immediate). b stays 0 (faithful torch bug) => one dense conv
// 64ci->128co, 5x5, pad 2; v = squash_z1(p/(8*cnt)); out [N, t1, z1, H, W].

#define CO 128

typedef __attribute__((ext_vector_type(8))) short bf16x8;
typedef __attribute__((ext_vector_type(4))) float f32x4;

// ---- W fp32 [t0][co][z0][5][5] -> Wr2 bf16 [kk][co][ci]
__global__ __launch_bounds__(256) void k_reorder(const float* __restrict__ Wsrc,
                                                 ushort* __restrict__ Wr2) {
    int idx = blockIdx.x * 256 + threadIdx.x;   // (kk*128+co)*64+ci
    if (idx >= 25 * 128 * 64) return;
    int ci = idx & 63;
    int r  = idx >> 6;
    int co = r & 127;
    int kk = r >> 7;
    int t0 = ci >> 4, z0 = ci & 15;
    __hip_bfloat16 b = __float2bfloat16(Wsrc[((t0 * CO + co) * 16 + z0) * 25 + kk]);
    Wr2[idx] = *(ushort*)&b;
}

// ---- u [n][ci][h][w] fp32 -> ut [n][h][w][ci] bf16 (LDS-tiled transpose)
__global__ __launch_bounds__(256) void k_pre(const float* __restrict__ u,
                                             ushort* __restrict__ ut) {
    __shared__ float lt[64][65];
    int b = blockIdx.x;              // (n*128 + h)*2 + wchunk
    int wc = b & 1; int nh = b >> 1; int h = nh & 127; int n = nh >> 7;
    int w0 = wc * 64;
    int t = threadIdx.x;
    int w = t & 63; int cg = t >> 6;
    const float* up = u + (size_t)n * (64 * 128 * 128) + h * 128 + w0 + w;
#pragma unroll
    for (int i = 0; i < 16; ++i) {
        int ci = cg * 16 + i;
        lt[w][ci] = up[(size_t)ci * (128 * 128)];
    }
    __syncthreads();
    int ci2 = t & 63; int pg = t >> 6;
    ushort* op = ut + (((size_t)(n * 128 + h)) * 128 + w0) * 64 + ci2;
#pragma unroll
    for (int i = 0; i < 16; ++i) {
        int w2 = pg * 16 + i;
        __hip_bfloat16 bv = __float2bfloat16(lt[w2][ci2]);
        op[(size_t)w2 * 64] = *(ushort*)&bv;
    }
}

// ---- main: grid 512 = 4(n) x 16(by: 8 rows) x 8(bx: 16 cols), 256 thr = 4 waves
// wave: wm4 = (wid>>1)*4 -> image rows [h0+wm4, +4); wn64 = (wid&1)*64 -> co.
// As/Bs row stride 80 ushorts (160 B): frag reads at dword 8*m16 mod 32 —
// the stride class that measured SQ_LDS_BANK_CONFLICT == 0 on HW (R4).
__global__ __launch_bounds__(256) void k_caps(const ushort* __restrict__ ut,
                                              const ushort* __restrict__ Wr2,
                                              float* __restrict__ out) {
    __shared__ ushort As[240 * 80];   // [p = rr*20+cc][ci pad] 38400 B
    __shared__ ushort Bs[128 * 80];   // [co][ci pad]           20480 B

    int tid = threadIdx.x;
    int bid = blockIdx.x;
    int bx = bid & 7, by = (bid >> 3) & 15, n = bid >> 7;
    int h0 = by * 8, w0 = bx * 16;

    // stage A tile (pad-2 halo, zero OOB): 240 pixels x 8 chunks of 8 ci
    for (int i = tid; i < 1920; i += 256) {
        int p = i >> 3, c = i & 7;
        int rr = p / 20, cc = p - rr * 20;
        int hh = h0 + rr - 2, ww = w0 + cc - 2;
        bf16x8 v = {};
        if ((unsigned)hh < 128u && (unsigned)ww < 128u)
            v = *(const bf16x8*)(ut + (((size_t)(n * 128 + hh)) * 128 + ww) * 64 + c * 8);
        *(bf16x8*)&As[p * 80 + c * 8] = v;
    }

    int lane = tid & 63, wid = tid >> 6;
    int wm4  = (wid >> 1) * 4;
    int wn64 = (wid & 1) * 64;
    int q = lane >> 4, m16 = lane & 15;

    f32x4 acc[4][4] = {};

    // register prefetch of B for kk=0
    bf16x8 pre[4];
#pragma unroll
    for (int j = 0; j < 4; ++j)
        pre[j] = *(const bf16x8*)(Wr2 + (size_t)(tid + j * 256) * 8);

    int aBase = (wm4 * 20 + m16) * 80 + q * 8;
    int bBase = (wn64 + m16) * 80 + q * 8;

#pragma unroll
    for (int kk = 0; kk < 25; ++kk) {
        const int kh = kk / 5, kw = kk % 5;
        __syncthreads();                 // compute(kk-1) done before Bs overwrite
#pragma unroll
        for (int j = 0; j < 4; ++j) {
            int i = tid + j * 256;
            *(bf16x8*)&Bs[(i >> 3) * 80 + (i & 7) * 8] = pre[j];
        }
        __syncthreads();
        if (kk < 24) {                   // overlap next-kk L2 load with compute
#pragma unroll
            for (int j = 0; j < 4; ++j)
                pre[j] = *(const bf16x8*)(Wr2 + (size_t)(kk + 1) * 8192 + (tid + j * 256) * 8);
        }
#pragma unroll
        for (int ks = 0; ks < 2; ++ks) {
            bf16x8 a[4], bb[4];
#pragma unroll
            for (int mi = 0; mi < 4; ++mi)
                a[mi] = *(const bf16x8*)&As[aBase + ((mi + kh) * 20 + kw) * 80 + ks * 32];
#pragma unroll
            for (int ni = 0; ni < 4; ++ni)
                bb[ni] = *(const bf16x8*)&Bs[bBase + ni * (16 * 80) + ks * 32];
#pragma unroll
            for (int mi = 0; mi < 4; ++mi)
#pragma unroll
                for (int ni = 0; ni < 4; ++ni)
                    acc[mi][ni] = __builtin_amdgcn_mfma_f32_16x16x32_bf16(
                        a[mi], bb[ni], acc[mi][ni], 0, 0, 0);
        }
    }

    // epilogue (R3-proven): scale 1/(8*cnt), squash over z1 (m16 lanes), store
    // D layout: row(m = image col) = q*4+reg, col(n = co) = m16
#pragma unroll
    for (int mi = 0; mi < 4; ++mi) {
        int h = h0 + wm4 + mi;
        int hlo = h - 2; if (hlo < 0) hlo = 0;
        int hhi = h + 2; if (hhi > 127) hhi = 127;
        float cnth = (float)(hhi - hlo + 1);
#pragma unroll
        for (int ni = 0; ni < 4; ++ni) {
            f32x4 cv = acc[mi][ni];
            float ov[4];
#pragma unroll
            for (int reg = 0; reg < 4; ++reg) {
                int w = w0 + q * 4 + reg;
                int wlo = w - 2; if (wlo < 0) wlo = 0;
                int whi = w + 2; if (whi > 127) whi = 127;
                float s = 1.f / (8.f * cnth * (float)(whi - wlo + 1));
                float pv = cv[reg] * s;
                float n2 = pv * pv;
                n2 += __shfl_xor(n2, 1);
                n2 += __shfl_xor(n2, 2);
                n2 += __shfl_xor(n2, 4);
                n2 += __shfl_xor(n2, 8);
                float fac = n2 / ((1.f + n2) * sqrtf(n2 + 1e-9f));
                ov[reg] = pv * fac;
            }
            int co = wn64 + ni * 16 + m16;
            *(float4*)(out + (((size_t)(n * CO + co)) << 14) + h * 128 + w0 + q * 4) =
                make_float4(ov[0], ov[1], ov[2], ov[3]);
        }
    }
}

extern "C" void kernel_launch(void* const* d_in, const int* in_sizes, int n_in,
                              void* d_out, int out_size, void* d_ws, size_t ws_size,
                              hipStream_t stream) {
    const float* u    = (const float*)d_in[0];
    const float* Wsrc = (const float*)d_in[1];
    float* out = (float*)d_out;
    ushort* Wr2 = (ushort*)d_ws;                       // 409600 B
    ushort* ut  = (ushort*)((char*)d_ws + 409600);     // 8388608 B

    k_reorder<<<800, 256, 0, stream>>>(Wsrc, Wr2);
    k_pre<<<1024, 256, 0, stream>>>(u, ut);
    k_caps<<<512, 256, 0, stream>>>(ut, Wr2, out);
}